// Round 3
// baseline (343.509 us; speedup 1.0000x reference)
//
#include <hip/hip_runtime.h>

// y[b, c*128+i] = sum_j x[b,c,j]*(R-Q)[i,j] + sum_j S[b,j]*Q[i,j],  S = sum_c x[b,c,:]
// Fused skinny GEMM, K=256, bf16 MFMA 16x16x32, one b-row per wave-iteration.

typedef __attribute__((ext_vector_type(4))) float  float4v;
typedef __attribute__((ext_vector_type(4))) float  f32x4;
typedef __attribute__((ext_vector_type(8))) short  short8;

__device__ inline unsigned short f2bf(float f) {
    unsigned u = __builtin_bit_cast(unsigned, f);
    u = (u + 0x7fffu + ((u >> 16) & 1u)) >> 16;   // round-to-nearest-even
    return (unsigned short)u;
}

__global__ __launch_bounds__(256, 2)
void cmix_kernel(const float* __restrict__ x, const float* __restrict__ R,
                 const float* __restrict__ Q, float* __restrict__ y) {
    // B-fragments of W^T (256x128) in MFMA order: WF[kk][n][lane] = 8 bf16,
    // elem j = Wt[kk*32 + (lane>>4)*8 + j][n*16 + (lane&15)]
    __shared__ short8 WF[8][8][64];

    const int tid = threadIdx.x;

    // ---- stage W = [R-Q | Q] into LDS in fragment order ----
    for (int idx = tid; idx < 4096; idx += 256) {
        const int l  = idx & 63;
        const int n  = (idx >> 6) & 7;
        const int kk = idx >> 9;
        const int i  = n * 16 + (l & 15);        // output feature (B-col)
        const int k  = kk * 32 + (l >> 4) * 8;   // K index (multiple of 8)
        short8 v;
        if (k < 128) {  // diagonal-block part: R - Q
            float4v r0 = *(const float4v*)(R + i * 128 + k);
            float4v r1 = *(const float4v*)(R + i * 128 + k + 4);
            float4v q0 = *(const float4v*)(Q + i * 128 + k);
            float4v q1 = *(const float4v*)(Q + i * 128 + k + 4);
#pragma unroll
            for (int j = 0; j < 4; ++j) {
                v[j]     = (short)f2bf(r0[j] - q0[j]);
                v[4 + j] = (short)f2bf(r1[j] - q1[j]);
            }
        } else {        // S part: Q
            float4v q0 = *(const float4v*)(Q + i * 128 + (k - 128));
            float4v q1 = *(const float4v*)(Q + i * 128 + (k - 128) + 4);
#pragma unroll
            for (int j = 0; j < 4; ++j) {
                v[j]     = (short)f2bf(q0[j]);
                v[4 + j] = (short)f2bf(q1[j]);
            }
        }
        WF[kk][n][l] = v;
    }
    __syncthreads();

    const int lane = tid & 63;
    const int w    = tid >> 6;
    const int c16  = lane & 15;   // channel (A-row / M), also B/D column
    const int g    = lane >> 4;   // k-group

    const int b_base = blockIdx.x * 16 + w * 4;

    for (int rr = 0; rr < 4; ++rr) {
        const int b = b_base + rr;
        const float* xr = x + (size_t)b * 2048;

        // ---- A-fragments (x part) straight from global: 8x float4 tile the row
        float4v xa[4][2];
#pragma unroll
        for (int t = 0; t < 4; ++t) {
            const float* p = xr + c16 * 128 + t * 32 + g * 8;
            xa[t][0] = *(const float4v*)(p);
            xa[t][1] = *(const float4v*)(p + 4);
        }

        // ---- pack x frags to bf16; butterfly-reduce 16-lane groups -> S frags
        short8 afr[8];
#pragma unroll
        for (int t = 0; t < 4; ++t) {
            float s[8];
#pragma unroll
            for (int j = 0; j < 8; ++j) s[j] = (j < 4) ? xa[t][0][j] : xa[t][1][j - 4];
            short8 av;
#pragma unroll
            for (int j = 0; j < 8; ++j) av[j] = (short)f2bf(s[j]);
            afr[t] = av;
#pragma unroll
            for (int m = 1; m <= 8; m <<= 1) {
#pragma unroll
                for (int j = 0; j < 8; ++j) s[j] += __shfl_xor(s[j], m, 64);
            }
            short8 sv;
#pragma unroll
            for (int j = 0; j < 8; ++j) sv[j] = (short)f2bf(s[j]);
            afr[4 + t] = sv;   // S[k'] octet, identical across the 16-lane group
        }

        // ---- MFMA: 8 K-steps x 8 N-tiles
        f32x4 acc[8];
#pragma unroll
        for (int n = 0; n < 8; ++n) acc[n] = (f32x4){0.f, 0.f, 0.f, 0.f};
#pragma unroll
        for (int kk = 0; kk < 8; ++kk) {
#pragma unroll
            for (int n = 0; n < 8; ++n) {
                acc[n] = __builtin_amdgcn_mfma_f32_16x16x32_bf16(
                    afr[kk], WF[kk][n][lane], acc[n], 0, 0, 0);
            }
        }

        // ---- store: D layout col=lane&15, row=(lane>>4)*4+r  (row == channel)
        float* yr = y + (size_t)b * 2048;
#pragma unroll
        for (int n = 0; n < 8; ++n) {
#pragma unroll
            for (int r = 0; r < 4; ++r) {
                yr[(g * 4 + r) * 128 + n * 16 + c16] = acc[n][r];
            }
        }
    }
}

extern "C" void kernel_launch(void* const* d_in, const int* in_sizes, int n_in,
                              void* d_out, int out_size, void* d_ws, size_t ws_size,
                              hipStream_t stream) {
    const float* x = (const float*)d_in[0];
    const float* R = (const float*)d_in[1];
    const float* Q = (const float*)d_in[2];
    float* y = (float*)d_out;
    // B=16384 rows, 16 rows per WG (4 waves x 4 rows), grid = 1024
    hipLaunchKernelGGL(cmix_kernel, dim3(1024), dim3(256), 0, stream, x, R, Q, y);
}